// Round 3
// baseline (17060.878 us; speedup 1.0000x reference)
//
#include <hip/hip_runtime.h>

// ---------------- problem constants ----------------
#define T_SEQ 80
#define NB    5120
#define NVOC  100

// ---------------- ws layout (bytes) ----------------
#define OFF_TABLE0 0u          // 100*1024*4  = 409600
#define OFF_BIAS1  409600u     // 1024*4      = 4096
#define OFF_BP0    413696u     // 256K*2      = 524288
#define OFF_BP1    937984u     // 512K*2      = 1048576
#define OFF_H1F    1986560u    // 5120*256*4  = 5242880
// total ~7.3 MB

typedef float  f32x4  __attribute__((ext_vector_type(4)));
typedef __bf16 bf16x8 __attribute__((ext_vector_type(8)));

// column permutation: n' -> original gate-major row index (i,f,g,o blocks of 256)
// np layout: [hgroup(16)][gate(4)][16 h-offsets]
__device__ __host__ __forceinline__ int colmap(int np) {
  int gate = (np >> 4) & 3;
  int j    = ((np >> 6) << 4) | (np & 15);
  return gate * 256 + j;
}

__device__ __forceinline__ unsigned short f2bf(float f) {
  unsigned int u = __float_as_uint(f);
  u += 0x7fffu + ((u >> 16) & 1u);   // round-to-nearest-even
  return (unsigned short)(u >> 16);
}

__device__ __forceinline__ float sigm(float x) {
  x = fminf(fmaxf(x, -20.f), 20.f);
  return 1.f / (1.f + __expf(-x));
}
__device__ __forceinline__ float tanh_(float x) {
  x = fminf(fmaxf(x, -10.f), 10.f);
  float e = __expf(2.f * x);
  return (e - 1.f) / (e + 1.f);
}

// ---------------- prep: tables + bf16 weight repack ----------------
// Bp0: [kc(8)][w(4)][ch(2)][nf(8)][lane(64)][i(8)]  (w_hh0, K=256)
// Bp1: [kc(16)][w(4)][ch(2)][nf(8)][lane(64)][i(8)] ([w_ih1 | w_hh1], K=512)
// elements: table0 102400 | bias1 1024 | Bp0 262144 | Bp1 524288 = 889856
__global__ void prep_kernel(const float* __restrict__ emb,
                            const float* __restrict__ w_ih0, const float* __restrict__ w_hh0,
                            const float* __restrict__ b_ih0, const float* __restrict__ b_hh0,
                            const float* __restrict__ w_ih1, const float* __restrict__ w_hh1,
                            const float* __restrict__ b_ih1, const float* __restrict__ b_hh1,
                            float* __restrict__ table0, float* __restrict__ bias1,
                            unsigned short* __restrict__ Bp0, unsigned short* __restrict__ Bp1) {
  int idx = blockIdx.x * 256 + threadIdx.x;
  if (idx < 102400) {
    int v = idx >> 10, np = idx & 1023;
    int row = colmap(np);
    float s = b_ih0[row] + b_hh0[row];
#pragma unroll
    for (int e = 0; e < 8; ++e) s = fmaf(emb[v * 8 + e], w_ih0[row * 8 + e], s);
    table0[idx] = s;
  } else if (idx < 103424) {
    int np = idx - 102400;
    bias1[np] = b_ih1[colmap(np)] + b_hh1[colmap(np)];
  } else if (idx < 365568) {
    int i2 = idx - 103424;
    int i = i2 & 7, lane = (i2 >> 3) & 63, nf = (i2 >> 9) & 7;
    int ch = (i2 >> 12) & 1, w = (i2 >> 13) & 3, kc = i2 >> 15;
    int k  = kc * 32 + ((lane >> 4) << 3) + i;
    int np = w * 256 + ch * 128 + nf * 16 + (lane & 15);
    int row = colmap(np);
    Bp0[i2] = f2bf(w_hh0[row * 256 + k]);
  } else if (idx < 889856) {
    int i2 = idx - 365568;
    int i = i2 & 7, lane = (i2 >> 3) & 63, nf = (i2 >> 9) & 7;
    int ch = (i2 >> 12) & 1, w = (i2 >> 13) & 3, kc = i2 >> 15;   // kc 0..15
    int k  = kc * 32 + ((lane >> 4) << 3) + i;
    int np = w * 256 + ch * 128 + nf * 16 + (lane & 15);
    int row = colmap(np);
    float val = (k < 256) ? w_ih1[row * 256 + k] : w_hh1[row * 256 + (k - 256)];
    Bp1[i2] = f2bf(val);
  }
}

// ---------------- persistent block-local LSTM ----------------
// grid = 160 blocks x 256 threads (4 waves, 1 block/CU, 1 wave/SIMD).
// Block owns 32 batch rows, FULL N=1024 gate cols both layers:
//   h0/h1 tiles live in LDS (block-local), c-states in VGPRs.
//   ZERO inter-block sync in the t-loop. B streams L2 -> registers -> MFMA.
// Wave w owns gate-cols [w*256,(w+1)*256) = h-cols [w*64,(w+1)*64).
__global__ __launch_bounds__(256, 1) void lstm_persistent(
    const int* __restrict__ x,
    const float* __restrict__ table0, const float* __restrict__ bias1,
    const unsigned short* __restrict__ Bp0, const unsigned short* __restrict__ Bp1,
    float* __restrict__ h1f) {
  __shared__ char h0t[16384];   // [32 rows][256 cols] bf16, XOR-swizzled
  __shared__ char h1t[16384];

  const int tid  = threadIdx.x;
  const int lane = tid & 63;
  const int wid  = tid >> 6;
  const int l15  = lane & 15;
  const int lhi  = lane >> 4;
  const int r0   = blockIdx.x * 32;

  // zero-init h state tiles (t = -1 state)
  {
    uint4 zz = {0, 0, 0, 0};
    uint4* p0 = (uint4*)h0t;
    uint4* p1 = (uint4*)h1t;
    for (int i = tid; i < 1024; i += 256) { p0[i] = zz; p1[i] = zz; }
  }

  // per-lane L1 bias: bbv[hg*4+g]
  float bbv[16];
#pragma unroll
  for (int j = 0; j < 16; ++j)
    bbv[j] = bias1[wid * 256 + (j >> 2) * 64 + (j & 3) * 16 + l15];

  float c0[32], c1[32];
#pragma unroll
  for (int j = 0; j < 32; ++j) { c0[j] = 0.f; c1[j] = 0.f; }

  f32x4  acc[2][16];
  bf16x8 bring[3][8];
  bf16x8 aL[2];

  __syncthreads();

  // slice source: 48 slices/step/wave; 0..15 = L0 (Bp0), 16..47 = L1 (Bp1)
#define SLICE_SRC(s_) (((s_) < 16) \
    ? (Bp0 + ((s_) >> 1) * 32768 + wid * 8192 + ((s_) & 1) * 4096) \
    : (Bp1 + (((s_) - 16) >> 1) * 32768 + wid * 8192 + (((s_) - 16) & 1) * 4096))

#define PREFETCH(s_) do { \
    const unsigned short* _src = SLICE_SRC(s_); \
    _Pragma("unroll") \
    for (int _nf = 0; _nf < 8; ++_nf) \
      bring[(s_) % 3][_nf] = *(const bf16x8*)(_src + ((_nf * 64 + lane) << 3)); \
  } while (0)

  // A-frag read from h tile: row = m*16+l15, k-bytes = kc*64 + lhi*16, XOR swizzle
#define READ_A(tile_, m_, kc_) \
    (*(const bf16x8*)((tile_) + (((((m_) * 16 + l15) << 9) + (kc_) * 64 + (lhi << 4)) ^ ((l15 & 7) << 4))))

#define COMPUTE(s_) do { \
    _Pragma("unroll") \
    for (int _nf = 0; _nf < 8; ++_nf) { \
      acc[0][((s_) & 1) * 8 + _nf] = __builtin_amdgcn_mfma_f32_16x16x32_bf16( \
          aL[0], bring[(s_) % 3][_nf], acc[0][((s_) & 1) * 8 + _nf], 0, 0, 0); \
      acc[1][((s_) & 1) * 8 + _nf] = __builtin_amdgcn_mfma_f32_16x16x32_bf16( \
          aL[1], bring[(s_) % 3][_nf], acc[1][((s_) & 1) * 8 + _nf], 0, 0, 0); \
    } } while (0)

  for (int t = 0; t < T_SEQ; ++t) {
    // x gathers for this step (8 rows per lane)
    int xr[8];
#pragma unroll
    for (int m = 0; m < 2; ++m)
#pragma unroll
      for (int r = 0; r < 4; ++r)
        xr[m * 4 + r] = x[t * NB + r0 + m * 16 + lhi * 4 + r];

    // ---------- L0 GEMM: gates[32 x 1024] += h0(t-1) @ Bp0 ----------
#pragma unroll
    for (int m = 0; m < 2; ++m)
#pragma unroll
      for (int j = 0; j < 16; ++j) acc[m][j] = (f32x4)0.f;

    PREFETCH(0); PREFETCH(1);
#pragma unroll
    for (int s = 0; s < 16; ++s) {
      if ((s & 1) == 0) { aL[0] = READ_A(h0t, 0, s >> 1); aL[1] = READ_A(h0t, 1, s >> 1); }
      PREFETCH(s + 2);                       // s=14,15 prefetch L1 slices 16,17
      COMPUTE(s);
    }

    __syncthreads();   // all waves done reading h0t(t-1)

    // ---------- epilogue L0: cell update, write h0t(t) ----------
#pragma unroll
    for (int m = 0; m < 2; ++m) {
#pragma unroll
      for (int r = 0; r < 4; ++r) {
        int row = m * 16 + lhi * 4 + r;
        const float* tb = table0 + xr[m * 4 + r] * 1024 + wid * 256 + l15;
#pragma unroll
        for (int hg = 0; hg < 4; ++hg) {
          float gi = acc[m][hg * 4 + 0][r] + tb[hg * 64 + 0];
          float gf = acc[m][hg * 4 + 1][r] + tb[hg * 64 + 16];
          float gg = acc[m][hg * 4 + 2][r] + tb[hg * 64 + 32];
          float go = acc[m][hg * 4 + 3][r] + tb[hg * 64 + 48];
          int ci = ((m * 4 + r) << 2) + hg;
          float cn = sigm(gf) * c0[ci] + sigm(gi) * tanh_(gg);
          c0[ci] = cn;
          float h = sigm(go) * tanh_(cn);
          int off = ((row << 9) + ((wid * 64 + hg * 16 + l15) << 1)) ^ ((row & 7) << 4);
          *(unsigned short*)(h0t + off) = f2bf(h);
        }
      }
    }
    __syncthreads();   // h0t(t) visible

    // ---------- L1 GEMM: gates[32 x 1024] = [h0(t)|h1(t-1)] @ Bp1 ----------
#pragma unroll
    for (int m = 0; m < 2; ++m)
#pragma unroll
      for (int j = 0; j < 16; ++j) acc[m][j] = (f32x4)0.f;

#pragma unroll
    for (int s = 16; s < 48; ++s) {
      if ((s & 1) == 0) {
        int kc1 = (s - 16) >> 1;
        const char* tl = (kc1 < 8) ? h0t : h1t;
        aL[0] = READ_A(tl, 0, kc1 & 7); aL[1] = READ_A(tl, 1, kc1 & 7);
      }
      if (s + 2 < 48) PREFETCH(s + 2);
      COMPUTE(s);
    }

    __syncthreads();   // all waves done reading h1t(t-1)

    // ---------- epilogue L1: cell update, write h1t(t) (+ h1f at t=79) ----------
#pragma unroll
    for (int m = 0; m < 2; ++m) {
#pragma unroll
      for (int r = 0; r < 4; ++r) {
        int row = m * 16 + lhi * 4 + r;
#pragma unroll
        for (int hg = 0; hg < 4; ++hg) {
          float gi = acc[m][hg * 4 + 0][r] + bbv[hg * 4 + 0];
          float gf = acc[m][hg * 4 + 1][r] + bbv[hg * 4 + 1];
          float gg = acc[m][hg * 4 + 2][r] + bbv[hg * 4 + 2];
          float go = acc[m][hg * 4 + 3][r] + bbv[hg * 4 + 3];
          int ci = ((m * 4 + r) << 2) + hg;
          float cn = sigm(gf) * c1[ci] + sigm(gi) * tanh_(gg);
          c1[ci] = cn;
          float h = sigm(go) * tanh_(cn);
          int hcol = wid * 64 + hg * 16 + l15;
          int off = ((row << 9) + (hcol << 1)) ^ ((row & 7) << 4);
          *(unsigned short*)(h1t + off) = f2bf(h);
          if (t == T_SEQ - 1) h1f[(size_t)(r0 + row) * 256 + hcol] = h;
        }
      }
    }
    // next step's syncs order h1t(t) before L1(t+1) reads
  }
#undef SLICE_SRC
#undef PREFETCH
#undef READ_A
#undef COMPUTE
}

// ---------------- decoder: out[64][100] = flat[64][20480] @ dec_w^T + dec_b ----------------
__global__ void decoder_kernel(const float* __restrict__ h1f,
                               const float* __restrict__ dec_w,
                               const float* __restrict__ dec_b,
                               float* __restrict__ out) {
  __shared__ float red[256];
  const int tid = threadIdx.x, lane = tid & 63, wid = tid >> 6;
  const int v = blockIdx.x;
  float dacc[64];
#pragma unroll
  for (int r = 0; r < 64; ++r) dacc[r] = 0.f;
  for (int q = tid; q < 20480; q += 256) {
    float w = dec_w[(size_t)v * 20480 + q];
    const float* fp = h1f + q;
#pragma unroll
    for (int r = 0; r < 64; ++r) dacc[r] = fmaf(fp[r * 20480], w, dacc[r]);
  }
#pragma unroll
  for (int r = 0; r < 64; ++r) {
    float s = dacc[r];
    for (int off = 32; off > 0; off >>= 1) s += __shfl_down(s, off, 64);
    if (lane == 0) red[wid * 64 + r] = s;
  }
  __syncthreads();
  if (tid < 64) {
    float s = red[tid] + red[64 + tid] + red[128 + tid] + red[192 + tid];
    out[tid * 100 + v] = s + dec_b[v];
  }
}

// ---------------- host launch ----------------
extern "C" void kernel_launch(void* const* d_in, const int* in_sizes, int n_in,
                              void* d_out, int out_size, void* d_ws, size_t ws_size,
                              hipStream_t stream) {
  const int*   x     = (const int*)d_in[0];
  const float* emb   = (const float*)d_in[1];
  const float* w_ih0 = (const float*)d_in[2];
  const float* w_hh0 = (const float*)d_in[3];
  const float* b_ih0 = (const float*)d_in[4];
  const float* b_hh0 = (const float*)d_in[5];
  const float* w_ih1 = (const float*)d_in[6];
  const float* w_hh1 = (const float*)d_in[7];
  const float* b_ih1 = (const float*)d_in[8];
  const float* b_hh1 = (const float*)d_in[9];
  const float* dec_w = (const float*)d_in[10];
  const float* dec_b = (const float*)d_in[11];
  float* out = (float*)d_out;
  char* ws = (char*)d_ws;

  float*          table0 = (float*)(ws + OFF_TABLE0);
  float*          bias1  = (float*)(ws + OFF_BIAS1);
  unsigned short* Bp0    = (unsigned short*)(ws + OFF_BP0);
  unsigned short* Bp1    = (unsigned short*)(ws + OFF_BP1);
  float*          h1f    = (float*)(ws + OFF_H1F);

  prep_kernel<<<3476, 256, 0, stream>>>(emb, w_ih0, w_hh0, b_ih0, b_hh0,
                                        w_ih1, w_hh1, b_ih1, b_hh1,
                                        table0, bias1, Bp0, Bp1);
  lstm_persistent<<<160, 256, 0, stream>>>(x, table0, bias1, Bp0, Bp1, h1f);
  decoder_kernel<<<NVOC, 256, 0, stream>>>(h1f, dec_w, dec_b, out);
}

// Round 4
// 7048.066 us; speedup vs baseline: 2.4206x; 2.4206x over previous
//
#include <hip/hip_runtime.h>

// ---------------- problem constants ----------------
#define T_SEQ 80
#define NB    5120
#define NVOC  100

// ---------------- ws layout (bytes) ----------------
#define OFF_TABLE0 0u          // 100*1024*4  = 409600
#define OFF_BIAS1  409600u     // 1024*4      = 4096
#define OFF_BP     413696u     // 786432*2    = 1572864  (granule-major B pack)
#define OFF_H1F    1986560u    // 5120*256*4  = 5242880
// total ~7.3 MB

// LDS: h0t 16K + h1t 16K + 8 waves * 3 slots * 4KB = 128KB
#define SMEM_BYTES 131072

typedef float  f32x4  __attribute__((ext_vector_type(4)));
typedef __bf16 bf16x8 __attribute__((ext_vector_type(8)));

// column permutation: n' -> original gate-major row index (i,f,g,o blocks of 256)
// np bit layout: [hgroup(np>>6)][gate(np>>4 &3)][np&15]
__device__ __host__ __forceinline__ int colmap(int np) {
  int gate = (np >> 4) & 3;
  int j    = ((np >> 6) << 4) | (np & 15);
  return gate * 256 + j;
}

__device__ __forceinline__ unsigned short f2bf(float f) {
  unsigned int u = __float_as_uint(f);
  u += 0x7fffu + ((u >> 16) & 1u);   // round-to-nearest-even
  return (unsigned short)(u >> 16);
}

__device__ __forceinline__ float sigm(float x) {
  x = fminf(fmaxf(x, -20.f), 20.f);
  return 1.f / (1.f + __expf(-x));
}
__device__ __forceinline__ float tanh_(float x) {
  x = fminf(fmaxf(x, -10.f), 10.f);
  float e = __expf(2.f * x);
  return (e - 1.f) / (e + 1.f);
}

// ---------------- prep: tables + bf16 weight repack ----------------
// Bp layout: [g:48][w:8][nf:4][lane:64][i:8] shorts.
//   granule g: L0 g<16: kc=g>>1, nh=g&1 (K=256, w_hh0)
//              L1 g>=16: kc=(g-16)>>1, nh=(g-16)&1 (K=512, [w_ih1|w_hh1])
//   np = w*128 + nh*64 + nf*16 + (lane&15);  k = kc*32 + (lane>>4)*8 + i
// elements: table0 102400 | bias1 1024 | Bp 786432 = 889856 = 3476*256
__global__ void prep_kernel(const float* __restrict__ emb,
                            const float* __restrict__ w_ih0, const float* __restrict__ w_hh0,
                            const float* __restrict__ b_ih0, const float* __restrict__ b_hh0,
                            const float* __restrict__ w_ih1, const float* __restrict__ w_hh1,
                            const float* __restrict__ b_ih1, const float* __restrict__ b_hh1,
                            float* __restrict__ table0, float* __restrict__ bias1,
                            unsigned short* __restrict__ Bp) {
  int idx = blockIdx.x * 256 + threadIdx.x;
  if (idx < 102400) {
    int v = idx >> 10, np = idx & 1023;
    int row = colmap(np);
    float s = b_ih0[row] + b_hh0[row];
#pragma unroll
    for (int e = 0; e < 8; ++e) s = fmaf(emb[v * 8 + e], w_ih0[row * 8 + e], s);
    table0[idx] = s;
  } else if (idx < 103424) {
    int np = idx - 102400;
    bias1[np] = b_ih1[colmap(np)] + b_hh1[colmap(np)];
  } else {
    int i2 = idx - 103424;            // < 786432
    int i    = i2 & 7;
    int lane = (i2 >> 3) & 63;
    int nf   = (i2 >> 9) & 3;
    int w    = (i2 >> 11) & 7;
    int g    = i2 >> 14;              // 0..47
    int np   = w * 128 + (g & 1) * 64 + nf * 16 + (lane & 15);
    int row  = colmap(np);
    float val;
    if (g < 16) {
      int k = (g >> 1) * 32 + (lane >> 4) * 8 + i;
      val = w_hh0[row * 256 + k];
    } else {
      int k = ((g - 16) >> 1) * 32 + (lane >> 4) * 8 + i;
      val = (k < 256) ? w_ih1[row * 256 + k] : w_hh1[row * 256 + (k - 256)];
    }
    Bp[i2] = f2bf(val);
  }
}

// raw barrier: ds ops visible, vmcnt NOT drained (keeps B-pipeline flowing)
__device__ __forceinline__ void bar_sync() {
  asm volatile("s_waitcnt lgkmcnt(0)" ::: "memory");
  __builtin_amdgcn_s_barrier();
}

// ---------------- persistent no-sync LSTM ----------------
// grid = 160 blocks x 512 threads (8 waves, 1 block/CU, 2 waves/SIMD).
// Block owns 32 batch rows, FULL N=1024, both layers. h0/h1 in LDS, c in VGPRs.
// ZERO inter-block communication. B streams global->LDS via global_load_lds into
// per-wave PRIVATE ring slices (no barriers in stream), counted vmcnt(8).
// Wave w owns gate-cols [w*128,(w+1)*128) = h-cols [w*32,+32).
__global__ __launch_bounds__(512, 1) void lstm_nosync(
    const int* __restrict__ x,
    const float* __restrict__ table0, const float* __restrict__ bias1,
    const unsigned short* __restrict__ Bp,
    float* __restrict__ h1f) {
  extern __shared__ char smem[];
  char* h0t = smem;              // [32][256] bf16, XOR-swizzled
  char* h1t = smem + 16384;

  const int tid  = threadIdx.x;
  const int lane = tid & 63;
  const int wid  = tid >> 6;     // 0..7
  const int l15  = lane & 15;
  const int lhi  = lane >> 4;
  const int r0   = blockIdx.x * 32;

  char* slice_base = smem + 32768 + wid * 12288;           // 3 x 4KB ring, private
  const char* bpw = (const char*)Bp + (wid << 12) + (lane << 4);

  // zero h tiles
  {
    uint4 zz = {0, 0, 0, 0};
    uint4* p = (uint4*)smem;
    for (int i = tid; i < 2048; i += 512) p[i] = zz;
  }

  // L1 bias per lane: bb[nh*4+gate]
  float bb[8];
#pragma unroll
  for (int nh = 0; nh < 2; ++nh)
#pragma unroll
    for (int g = 0; g < 4; ++g)
      bb[nh * 4 + g] = bias1[wid * 128 + nh * 64 + g * 16 + l15];

  int xr[8];
#pragma unroll
  for (int mr = 0; mr < 8; ++mr)
    xr[mr] = x[r0 + (mr >> 2) * 16 + lhi * 4 + (mr & 3)];

  float c0[16], c1[16];
#pragma unroll
  for (int j = 0; j < 16; ++j) { c0[j] = 0.f; c1[j] = 0.f; }

  f32x4  acc[2][2][4];   // [m][nh][gate]
  bf16x8 a0, a1;

#define STAGE(s_) do { \
    int _ss = (s_) % 48, _slot = (s_) % 3; \
    const char* _g = bpw + _ss * 32768; \
    char* _l = slice_base + _slot * 4096; \
    _Pragma("unroll") \
    for (int _j = 0; _j < 4; ++_j) \
      __builtin_amdgcn_global_load_lds( \
          (const __attribute__((address_space(1))) void*)(_g + _j * 1024), \
          (__attribute__((address_space(3))) void*)(_l + _j * 1024), 16, 0, 0); \
  } while (0)

#define READ_A(tile_, m_, kc_) \
    (*(const bf16x8*)((tile_) + (((((m_) * 16 + l15) << 9) + (kc_) * 64 + (lhi << 4)) ^ ((l15 & 7) << 4))))

#define GRANULE(g_, tl_, kcL_) do { \
    STAGE((g_) + 2); \
    asm volatile("s_waitcnt vmcnt(8)" ::: "memory"); \
    if (((g_) & 1) == 0) { a0 = READ_A(tl_, 0, kcL_); a1 = READ_A(tl_, 1, kcL_); } \
    const char* _sl = slice_base + ((g_) % 3) * 4096; \
    _Pragma("unroll") \
    for (int _nf = 0; _nf < 4; ++_nf) { \
      bf16x8 _b = *(const bf16x8*)(_sl + _nf * 1024 + (lane << 4)); \
      acc[0][(g_) & 1][_nf] = __builtin_amdgcn_mfma_f32_16x16x32_bf16(a0, _b, acc[0][(g_) & 1][_nf], 0, 0, 0); \
      acc[1][(g_) & 1][_nf] = __builtin_amdgcn_mfma_f32_16x16x32_bf16(a1, _b, acc[1][(g_) & 1][_nf], 0, 0, 0); \
    } \
  } while (0)

  // prologue stages; __syncthreads also publishes zeroed h tiles
  STAGE(0); STAGE(1);
  __syncthreads();

  for (int t = 0; t < T_SEQ; ++t) {
    // table gathers for this step (f32, coalesced 64B per 16-lane group)
    float tbv[8][8];
#pragma unroll
    for (int mr = 0; mr < 8; ++mr) {
      const float* tb = table0 + xr[mr] * 1024 + wid * 128 + l15;
#pragma unroll
      for (int nh = 0; nh < 2; ++nh)
#pragma unroll
        for (int g = 0; g < 4; ++g)
          tbv[mr][nh * 4 + g] = tb[nh * 64 + g * 16];
    }
    // x prefetch for next step (in-bounds clamp at t=79)
    {
      int tn = (t < T_SEQ - 1) ? (t + 1) : t;
#pragma unroll
      for (int mr = 0; mr < 8; ++mr)
        xr[mr] = x[tn * NB + r0 + (mr >> 2) * 16 + lhi * 4 + (mr & 3)];
    }

    // ---------- L0 GEMM: granules 0..15 (A = h0(t-1)) ----------
#pragma unroll
    for (int m = 0; m < 2; ++m)
#pragma unroll
      for (int nh = 0; nh < 2; ++nh)
#pragma unroll
        for (int nf = 0; nf < 4; ++nf) acc[m][nh][nf] = (f32x4)0.f;
#pragma unroll
    for (int g = 0; g < 16; ++g) GRANULE(g, h0t, (g >> 1));

    bar_sync();   // all waves done reading h0t(t-1)

    // ---------- epilogue L0: cell update -> h0t(t) ----------
#pragma unroll
    for (int m = 0; m < 2; ++m) {
#pragma unroll
      for (int r = 0; r < 4; ++r) {
        int row = m * 16 + lhi * 4 + r;
#pragma unroll
        for (int nh = 0; nh < 2; ++nh) {
          float gi = acc[m][nh][0][r] + tbv[m * 4 + r][nh * 4 + 0];
          float gf = acc[m][nh][1][r] + tbv[m * 4 + r][nh * 4 + 1];
          float gg = acc[m][nh][2][r] + tbv[m * 4 + r][nh * 4 + 2];
          float go = acc[m][nh][3][r] + tbv[m * 4 + r][nh * 4 + 3];
          int ci = (m * 4 + r) * 2 + nh;
          float cn = sigm(gf) * c0[ci] + sigm(gi) * tanh_(gg);
          c0[ci] = cn;
          float h = sigm(go) * tanh_(cn);
          int hc = (wid * 2 + nh) * 16 + l15;
          *(unsigned short*)(h0t + (((row << 9) + (hc << 1)) ^ ((row & 7) << 4))) = f2bf(h);
        }
      }
    }
    bar_sync();   // h0t(t) visible

    // ---------- L1 GEMM: granules 16..47 (A = [h0(t) | h1(t-1)]) ----------
#pragma unroll
    for (int m = 0; m < 2; ++m)
#pragma unroll
      for (int nh = 0; nh < 2; ++nh)
#pragma unroll
        for (int nf = 0; nf < 4; ++nf) acc[m][nh][nf] = (f32x4)0.f;
#pragma unroll
    for (int g = 16; g < 48; ++g) {
      const int kc = (g - 16) >> 1;
      const char* tl = (kc < 8) ? h0t : h1t;
      GRANULE(g, tl, (kc & 7));
    }
    bar_sync();   // all waves done reading h1t(t-1)

    // ---------- epilogue L1: cell update -> h1t(t) (+ h1f at t=79) ----------
#pragma unroll
    for (int m = 0; m < 2; ++m) {
#pragma unroll
      for (int r = 0; r < 4; ++r) {
        int row = m * 16 + lhi * 4 + r;
#pragma unroll
        for (int nh = 0; nh < 2; ++nh) {
          float gi = acc[m][nh][0][r] + bb[nh * 4 + 0];
          float gf = acc[m][nh][1][r] + bb[nh * 4 + 1];
          float gg = acc[m][nh][2][r] + bb[nh * 4 + 2];
          float go = acc[m][nh][3][r] + bb[nh * 4 + 3];
          int ci = (m * 4 + r) * 2 + nh;
          float cn = sigm(gf) * c1[ci] + sigm(gi) * tanh_(gg);
          c1[ci] = cn;
          float h = sigm(go) * tanh_(cn);
          int hc = (wid * 2 + nh) * 16 + l15;
          *(unsigned short*)(h1t + (((row << 9) + (hc << 1)) ^ ((row & 7) << 4))) = f2bf(h);
          if (t == T_SEQ - 1) h1f[(size_t)(r0 + row) * 256 + hc] = h;
        }
      }
    }
    // no 4th barrier: next step's bar1/bar2 order epi1 writes before their readers
  }

  asm volatile("s_waitcnt vmcnt(0)" ::: "memory");   // drain dangling prefetch stages
#undef STAGE
#undef READ_A
#undef GRANULE
}

// ---------------- decoder: out[64][100] = flat[64][20480] @ dec_w^T + dec_b ----------------
__global__ void decoder_kernel(const float* __restrict__ h1f,
                               const float* __restrict__ dec_w,
                               const float* __restrict__ dec_b,
                               float* __restrict__ out) {
  __shared__ float red[256];
  const int tid = threadIdx.x, lane = tid & 63, wid = tid >> 6;
  const int v = blockIdx.x;
  float dacc[64];
#pragma unroll
  for (int r = 0; r < 64; ++r) dacc[r] = 0.f;
  for (int q = tid; q < 20480; q += 256) {
    float w = dec_w[(size_t)v * 20480 + q];
    const float* fp = h1f + q;
#pragma unroll
    for (int r = 0; r < 64; ++r) dacc[r] = fmaf(fp[r * 20480], w, dacc[r]);
  }
#pragma unroll
  for (int r = 0; r < 64; ++r) {
    float s = dacc[r];
    for (int off = 32; off > 0; off >>= 1) s += __shfl_down(s, off, 64);
    if (lane == 0) red[wid * 64 + r] = s;
  }
  __syncthreads();
  if (tid < 64) {
    float s = red[tid] + red[64 + tid] + red[128 + tid] + red[192 + tid];
    out[tid * 100 + v] = s + dec_b[v];
  }
}

// ---------------- host launch ----------------
extern "C" void kernel_launch(void* const* d_in, const int* in_sizes, int n_in,
                              void* d_out, int out_size, void* d_ws, size_t ws_size,
                              hipStream_t stream) {
  const int*   x     = (const int*)d_in[0];
  const float* emb   = (const float*)d_in[1];
  const float* w_ih0 = (const float*)d_in[2];
  const float* w_hh0 = (const float*)d_in[3];
  const float* b_ih0 = (const float*)d_in[4];
  const float* b_hh0 = (const float*)d_in[5];
  const float* w_ih1 = (const float*)d_in[6];
  const float* w_hh1 = (const float*)d_in[7];
  const float* b_ih1 = (const float*)d_in[8];
  const float* b_hh1 = (const float*)d_in[9];
  const float* dec_w = (const float*)d_in[10];
  const float* dec_b = (const float*)d_in[11];
  float* out = (float*)d_out;
  char* ws = (char*)d_ws;

  float*          table0 = (float*)(ws + OFF_TABLE0);
  float*          bias1  = (float*)(ws + OFF_BIAS1);
  unsigned short* Bp     = (unsigned short*)(ws + OFF_BP);
  float*          h1f    = (float*)(ws + OFF_H1F);

  prep_kernel<<<3476, 256, 0, stream>>>(emb, w_ih0, w_hh0, b_ih0, b_hh0,
                                        w_ih1, w_hh1, b_ih1, b_hh1,
                                        table0, bias1, Bp);
  hipFuncSetAttribute((const void*)lstm_nosync,
                      hipFuncAttributeMaxDynamicSharedMemorySize, SMEM_BYTES);
  lstm_nosync<<<160, 512, SMEM_BYTES, stream>>>(x, table0, bias1, Bp, h1f);
  decoder_kernel<<<NVOC, 256, 0, stream>>>(h1f, dec_w, dec_b, out);
}

// Round 5
// 6588.663 us; speedup vs baseline: 2.5894x; 1.0697x over previous
//
#include <hip/hip_runtime.h>

// ---------------- problem constants ----------------
#define T_SEQ 80
#define NB    5120
#define NVOC  100

// ---------------- ws layout (bytes) ----------------
#define OFF_TABLE0 0u          // 100*1024*4  = 409600
#define OFF_BIAS1  409600u     // 1024*4      = 4096
#define OFF_BP     413696u     // 786432*2    = 1572864  (granule-major B pack)
#define OFF_H1F    1986560u    // 5120*256*4  = 5242880
// total ~7.3 MB

typedef float  f32x4  __attribute__((ext_vector_type(4)));
typedef __bf16 bf16x8 __attribute__((ext_vector_type(8)));

// column permutation: n' -> original gate-major row index (i,f,g,o blocks of 256)
__device__ __host__ __forceinline__ int colmap(int np) {
  int gate = (np >> 4) & 3;
  int j    = ((np >> 6) << 4) | (np & 15);
  return gate * 256 + j;
}

__device__ __forceinline__ unsigned short f2bf(float f) {
  unsigned int u = __float_as_uint(f);
  u += 0x7fffu + ((u >> 16) & 1u);   // round-to-nearest-even
  return (unsigned short)(u >> 16);
}

__device__ __forceinline__ float sigm(float x) {
  x = fminf(fmaxf(x, -20.f), 20.f);
  return 1.f / (1.f + __expf(-x));
}
__device__ __forceinline__ float tanh_(float x) {
  x = fminf(fmaxf(x, -10.f), 10.f);
  float e = __expf(2.f * x);
  return (e - 1.f) / (e + 1.f);
}

// ---------------- prep: tables + bf16 weight repack ----------------
// Bp layout: [g:48][w:8][nf:4][lane:64][i:8] shorts.
//   granule g: L0 g<16: kc=g>>1, nh=g&1 (K=256, w_hh0)
//              L1 g>=16: kc=(g-16)>>1, nh=(g-16)&1 (K=512, [w_ih1|w_hh1])
//   np = w*128 + nh*64 + nf*16 + (lane&15);  k = kc*32 + (lane>>4)*8 + i
// elements: table0 102400 | bias1 1024 | Bp 786432 = 889856 = 3476*256
__global__ void prep_kernel(const float* __restrict__ emb,
                            const float* __restrict__ w_ih0, const float* __restrict__ w_hh0,
                            const float* __restrict__ b_ih0, const float* __restrict__ b_hh0,
                            const float* __restrict__ w_ih1, const float* __restrict__ w_hh1,
                            const float* __restrict__ b_ih1, const float* __restrict__ b_hh1,
                            float* __restrict__ table0, float* __restrict__ bias1,
                            unsigned short* __restrict__ Bp) {
  int idx = blockIdx.x * 256 + threadIdx.x;
  if (idx < 102400) {
    int v = idx >> 10, np = idx & 1023;
    int row = colmap(np);
    float s = b_ih0[row] + b_hh0[row];
#pragma unroll
    for (int e = 0; e < 8; ++e) s = fmaf(emb[v * 8 + e], w_ih0[row * 8 + e], s);
    table0[idx] = s;
  } else if (idx < 103424) {
    int np = idx - 102400;
    bias1[np] = b_ih1[colmap(np)] + b_hh1[colmap(np)];
  } else {
    int i2 = idx - 103424;            // < 786432
    int i    = i2 & 7;
    int lane = (i2 >> 3) & 63;
    int nf   = (i2 >> 9) & 3;
    int w    = (i2 >> 11) & 7;
    int g    = i2 >> 14;              // 0..47
    int np   = w * 128 + (g & 1) * 64 + nf * 16 + (lane & 15);
    int row  = colmap(np);
    float val;
    if (g < 16) {
      int k = (g >> 1) * 32 + (lane >> 4) * 8 + i;
      val = w_hh0[row * 256 + k];
    } else {
      int k = ((g - 16) >> 1) * 32 + (lane >> 4) * 8 + i;
      val = (k < 256) ? w_ih1[row * 256 + k] : w_hh1[row * 256 + (k - 256)];
    }
    Bp[i2] = f2bf(val);
  }
}

// raw barrier: LDS ops visible, vmcnt NOT drained (keeps B register-pipeline flowing)
__device__ __forceinline__ void bar_sync() {
  asm volatile("s_waitcnt lgkmcnt(0)" ::: "memory");
  __builtin_amdgcn_s_barrier();
}

// ---------------- persistent no-sync LSTM ----------------
// grid = 160 blocks x 512 threads (8 waves, 1 block/CU, 2 waves/SIMD).
// Block owns 32 batch rows, FULL N=1024, both layers. h0/h1 in LDS, c in VGPRs.
// ZERO inter-block communication. B streams global(L2) -> VGPR ring (plain loads,
// depth-4, issue g+3 while consuming g) -> MFMA. No LDS hop for B.
// Wave w owns gate-cols [w*128,(w+1)*128) = h-cols [w*32,+32).
__global__ __launch_bounds__(512, 1) void lstm_nosync(
    const int* __restrict__ x,
    const float* __restrict__ table0, const float* __restrict__ bias1,
    const unsigned short* __restrict__ Bp,
    float* __restrict__ h1f) {
  __shared__ char h0t[16384];   // [32][256] bf16, XOR-swizzled
  __shared__ char h1t[16384];

  const int tid  = threadIdx.x;
  const int lane = tid & 63;
  const int wid  = tid >> 6;     // 0..7
  const int l15  = lane & 15;
  const int lhi  = lane >> 4;
  const int r0   = blockIdx.x * 32;

  const char* bpw = (const char*)Bp + (wid << 12) + (lane << 4);

  // zero h tiles
  {
    uint4 zz = {0, 0, 0, 0};
    uint4* p0 = (uint4*)h0t;
    uint4* p1 = (uint4*)h1t;
    for (int i = tid; i < 1024; i += 512) { p0[i] = zz; p1[i] = zz; }
  }

  // L1 bias per lane: bb[nh*4+gate]
  float bb[8];
#pragma unroll
  for (int nh = 0; nh < 2; ++nh)
#pragma unroll
    for (int g = 0; g < 4; ++g)
      bb[nh * 4 + g] = bias1[wid * 128 + nh * 64 + g * 16 + l15];

  int xr[8];
#pragma unroll
  for (int mr = 0; mr < 8; ++mr)
    xr[mr] = x[r0 + (mr >> 2) * 16 + lhi * 4 + (mr & 3)];

  float c0[16], c1[16];
#pragma unroll
  for (int j = 0; j < 16; ++j) { c0[j] = 0.f; c1[j] = 0.f; }

  f32x4  acc[2][2][4];   // [m][nh][gate]
  bf16x8 bring[4][4];    // register ring: [slot][nf]
  bf16x8 a0, a1;

  // load granule slice s into ring slot s&3 (plain global loads -> VGPR)
#define LOADB(s_) do { \
    const char* _g = bpw + ((s_) % 48) * 32768; \
    _Pragma("unroll") \
    for (int _nf = 0; _nf < 4; ++_nf) \
      bring[(s_) & 3][_nf] = *(const bf16x8*)(_g + _nf * 1024); \
  } while (0)

#define READ_A(tile_, m_, kc_) \
    (*(const bf16x8*)((tile_) + (((((m_) * 16 + l15) << 9) + (kc_) * 64 + (lhi << 4)) ^ ((l15 & 7) << 4))))

#define GRANULE(g_, tl_, kcL_) do { \
    if (((g_) & 1) == 0) { a0 = READ_A(tl_, 0, kcL_); a1 = READ_A(tl_, 1, kcL_); } \
    LOADB((g_) + 3); \
    _Pragma("unroll") \
    for (int _nf = 0; _nf < 4; ++_nf) { \
      acc[0][(g_) & 1][_nf] = __builtin_amdgcn_mfma_f32_16x16x32_bf16(a0, bring[(g_) & 3][_nf], acc[0][(g_) & 1][_nf], 0, 0, 0); \
      acc[1][(g_) & 1][_nf] = __builtin_amdgcn_mfma_f32_16x16x32_bf16(a1, bring[(g_) & 3][_nf], acc[1][(g_) & 1][_nf], 0, 0, 0); \
    } \
  } while (0)

  // prologue: fill 3 ring slots; __syncthreads publishes zeroed h tiles
  LOADB(0); LOADB(1); LOADB(2);
  __syncthreads();

  for (int t = 0; t < T_SEQ; ++t) {
    // table gathers for this step (f32, 64B-chunk coalesced per 16-lane group)
    float tbv[8][8];
#pragma unroll
    for (int mr = 0; mr < 8; ++mr) {
      const float* tb = table0 + xr[mr] * 1024 + wid * 128 + l15;
#pragma unroll
      for (int nh = 0; nh < 2; ++nh)
#pragma unroll
        for (int g = 0; g < 4; ++g)
          tbv[mr][nh * 4 + g] = tb[nh * 64 + g * 16];
    }
    // x prefetch for next step
    {
      int tn = (t < T_SEQ - 1) ? (t + 1) : t;
#pragma unroll
      for (int mr = 0; mr < 8; ++mr)
        xr[mr] = x[tn * NB + r0 + (mr >> 2) * 16 + lhi * 4 + (mr & 3)];
    }

    // ---------- L0 GEMM: granules 0..15 (A = h0(t-1)) ----------
#pragma unroll
    for (int m = 0; m < 2; ++m)
#pragma unroll
      for (int nh = 0; nh < 2; ++nh)
#pragma unroll
        for (int nf = 0; nf < 4; ++nf) acc[m][nh][nf] = (f32x4)0.f;
#pragma unroll
    for (int g = 0; g < 16; ++g) GRANULE(g, h0t, (g >> 1));

    bar_sync();   // all waves done reading h0t(t-1)

    // ---------- epilogue L0: cell update -> h0t(t) ----------
#pragma unroll
    for (int m = 0; m < 2; ++m) {
#pragma unroll
      for (int r = 0; r < 4; ++r) {
        int row = m * 16 + lhi * 4 + r;
#pragma unroll
        for (int nh = 0; nh < 2; ++nh) {
          float gi = acc[m][nh][0][r] + tbv[m * 4 + r][nh * 4 + 0];
          float gf = acc[m][nh][1][r] + tbv[m * 4 + r][nh * 4 + 1];
          float gg = acc[m][nh][2][r] + tbv[m * 4 + r][nh * 4 + 2];
          float go = acc[m][nh][3][r] + tbv[m * 4 + r][nh * 4 + 3];
          int ci = (m * 4 + r) * 2 + nh;
          float cn = sigm(gf) * c0[ci] + sigm(gi) * tanh_(gg);
          c0[ci] = cn;
          float h = sigm(go) * tanh_(cn);
          int hc = (wid * 2 + nh) * 16 + l15;
          *(unsigned short*)(h0t + (((row << 9) + (hc << 1)) ^ ((row & 7) << 4))) = f2bf(h);
        }
      }
    }
    bar_sync();   // h0t(t) visible

    // ---------- L1 GEMM: granules 16..47 (A = [h0(t) | h1(t-1)]) ----------
#pragma unroll
    for (int m = 0; m < 2; ++m)
#pragma unroll
      for (int nh = 0; nh < 2; ++nh)
#pragma unroll
        for (int nf = 0; nf < 4; ++nf) acc[m][nh][nf] = (f32x4)0.f;
#pragma unroll
    for (int g = 16; g < 48; ++g) {
      const int kc = (g - 16) >> 1;
      const char* tl = (kc < 8) ? h0t : h1t;
      GRANULE(g, tl, (kc & 7));
    }
    bar_sync();   // all waves done reading h1t(t-1)

    // ---------- epilogue L1: cell update -> h1t(t) (+ h1f at t=79) ----------
#pragma unroll
    for (int m = 0; m < 2; ++m) {
#pragma unroll
      for (int r = 0; r < 4; ++r) {
        int row = m * 16 + lhi * 4 + r;
#pragma unroll
        for (int nh = 0; nh < 2; ++nh) {
          float gi = acc[m][nh][0][r] + bb[nh * 4 + 0];
          float gf = acc[m][nh][1][r] + bb[nh * 4 + 1];
          float gg = acc[m][nh][2][r] + bb[nh * 4 + 2];
          float go = acc[m][nh][3][r] + bb[nh * 4 + 3];
          int ci = (m * 4 + r) * 2 + nh;
          float cn = sigm(gf) * c1[ci] + sigm(gi) * tanh_(gg);
          c1[ci] = cn;
          float h = sigm(go) * tanh_(cn);
          int hc = (wid * 2 + nh) * 16 + l15;
          *(unsigned short*)(h1t + (((row << 9) + (hc << 1)) ^ ((row & 7) << 4))) = f2bf(h);
          if (t == T_SEQ - 1) h1f[(size_t)(r0 + row) * 256 + hc] = h;
        }
      }
    }
    // no 4th barrier: next step's bar1/bar2 order epi1 writes before their readers
  }
#undef LOADB
#undef READ_A
#undef GRANULE
}

// ---------------- decoder: out[64][100] = flat[64][20480] @ dec_w^T + dec_b ----------------
__global__ void decoder_kernel(const float* __restrict__ h1f,
                               const float* __restrict__ dec_w,
                               const float* __restrict__ dec_b,
                               float* __restrict__ out) {
  __shared__ float red[256];
  const int tid = threadIdx.x, lane = tid & 63, wid = tid >> 6;
  const int v = blockIdx.x;
  float dacc[64];
#pragma unroll
  for (int r = 0; r < 64; ++r) dacc[r] = 0.f;
  for (int q = tid; q < 20480; q += 256) {
    float w = dec_w[(size_t)v * 20480 + q];
    const float* fp = h1f + q;
#pragma unroll
    for (int r = 0; r < 64; ++r) dacc[r] = fmaf(fp[r * 20480], w, dacc[r]);
  }
#pragma unroll
  for (int r = 0; r < 64; ++r) {
    float s = dacc[r];
    for (int off = 32; off > 0; off >>= 1) s += __shfl_down(s, off, 64);
    if (lane == 0) red[wid * 64 + r] = s;
  }
  __syncthreads();
  if (tid < 64) {
    float s = red[tid] + red[64 + tid] + red[128 + tid] + red[192 + tid];
    out[tid * 100 + v] = s + dec_b[v];
  }
}

// ---------------- host launch ----------------
extern "C" void kernel_launch(void* const* d_in, const int* in_sizes, int n_in,
                              void* d_out, int out_size, void* d_ws, size_t ws_size,
                              hipStream_t stream) {
  const int*   x     = (const int*)d_in[0];
  const float* emb   = (const float*)d_in[1];
  const float* w_ih0 = (const float*)d_in[2];
  const float* w_hh0 = (const float*)d_in[3];
  const float* b_ih0 = (const float*)d_in[4];
  const float* b_hh0 = (const float*)d_in[5];
  const float* w_ih1 = (const float*)d_in[6];
  const float* w_hh1 = (const float*)d_in[7];
  const float* b_ih1 = (const float*)d_in[8];
  const float* b_hh1 = (const float*)d_in[9];
  const float* dec_w = (const float*)d_in[10];
  const float* dec_b = (const float*)d_in[11];
  float* out = (float*)d_out;
  char* ws = (char*)d_ws;

  float*          table0 = (float*)(ws + OFF_TABLE0);
  float*          bias1  = (float*)(ws + OFF_BIAS1);
  unsigned short* Bp     = (unsigned short*)(ws + OFF_BP);
  float*          h1f    = (float*)(ws + OFF_H1F);

  prep_kernel<<<3476, 256, 0, stream>>>(emb, w_ih0, w_hh0, b_ih0, b_hh0,
                                        w_ih1, w_hh1, b_ih1, b_hh1,
                                        table0, bias1, Bp);
  lstm_nosync<<<160, 512, 0, stream>>>(x, table0, bias1, Bp, h1f);
  decoder_kernel<<<NVOC, 256, 0, stream>>>(h1f, dec_w, dec_b, out);
}